// Round 10
// baseline (216.996 us; speedup 1.0000x reference)
//
#include <hip/hip_runtime.h>

#define NTOK 160
#define EDIM 256
#define HH 4
#define NNR 25600          // NTOK*NTOK rows
#define PC 784             // packed projection cols
#define YBC 768            // bf16 matmul cols of Y
#define SCALEF 0.125f
#define LOG2E 1.44269504f
#define LNEPS 1e-5f

// ---- workspace layout (float offsets) ----
#define OFF_ELN 0LL                       // bf16 [NNR][256]
#define OFF_YBF (OFF_ELN + 3276800LL)     // bf16 [NNR][768]
#define OFF_WPT (OFF_YBF + 9830400LL)     // bf16 [784][256]
#define OFF_BP  (OFF_WPT + 100352LL)      // fp32 [784]
#define OFF_WOT (OFF_BP  + 800LL)         // bf16 [256][512]
#define OFF_BGI (OFF_WOT + 65536LL)       // half2 [4][NNR]  (bias*log2e, gate)
#define OFF_BGO (OFF_BGI + 102400LL)      // half2 [4][NNR]
#define OFF_VAB (OFF_BGO + 102400LL)      // bf16 [NNR][512]

#define LN_BLOCKS 6400
#define PACK_TOTAL (PC * 256 + PC + 256 * 512)   // 331,792
#define PACK_BLOCKS ((PACK_TOTAL + 255) / 256)   // 1297

typedef short bf16x8 __attribute__((ext_vector_type(8)));
typedef unsigned short u16x8 __attribute__((ext_vector_type(8)));
typedef unsigned short u16x4 __attribute__((ext_vector_type(4)));
typedef float f32x4 __attribute__((ext_vector_type(4)));

__device__ __forceinline__ unsigned short bf16_rne(float f) {
  unsigned int u = __float_as_uint(f);
  u += 0x7FFFu + ((u >> 16) & 1u);
  return (unsigned short)(u >> 16);
}
__device__ __forceinline__ unsigned int pack_bf16(float lo, float hi) {
  return (unsigned int)bf16_rne(lo) | ((unsigned int)bf16_rne(hi) << 16);
}
__device__ __forceinline__ unsigned short f2h(float f) {
  _Float16 h = (_Float16)f;
  return *(unsigned short*)&h;
}
__device__ __forceinline__ float h2f(unsigned short u) {
  _Float16 h = *(_Float16*)&u;
  return (float)h;
}

__device__ __forceinline__ float wave_sum(float v) {
  #pragma unroll
  for (int o = 1; o < 64; o <<= 1) v += __shfl_xor(v, o, 64);
  return v;
}

// packed col map n: [0,256) Qin(h-major, *SCALE*log2e) | [256,320) Kin | [320,384) Vin |
// [384,640) Qout | [640,704) Kout | [704,768) Vout |
// [768,772) E_in | [772,776) G_in | [776,780) E_out | [780,784) G_out
__device__ __forceinline__ void col_map(int n, const float* const* W, const float* const* bia,
                                        const float** Wsel, const float** bsel,
                                        int* col, int* ld, float* scale) {
  *scale = 1.f;
  if (n < 256)      { *Wsel = W[0]; *bsel = bia[0]; *col = (n&63)*4 + (n>>6); *ld = 256; *scale = SCALEF * LOG2E; }
  else if (n < 320) { *Wsel = W[1]; *bsel = bia[1]; *col = n - 256;        *ld = 128; }
  else if (n < 384) { *Wsel = W[1]; *bsel = bia[1]; *col = 64 + n - 320;   *ld = 128; }
  else if (n < 640) { int c2 = n - 384; *Wsel = W[3]; *bsel = bia[3]; *col = (c2&63)*4 + (c2>>6); *ld = 256; *scale = SCALEF * LOG2E; }
  else if (n < 704) { *Wsel = W[4]; *bsel = bia[4]; *col = n - 640;        *ld = 128; }
  else if (n < 768) { *Wsel = W[4]; *bsel = bia[4]; *col = 64 + n - 704;   *ld = 128; }
  else if (n < 772) { *Wsel = W[2]; *bsel = bia[2]; *col = n - 768;        *ld = 8; }
  else if (n < 776) { *Wsel = W[2]; *bsel = bia[2]; *col = 4 + n - 772;    *ld = 8; }
  else if (n < 780) { *Wsel = W[5]; *bsel = bia[5]; *col = n - 776;        *ld = 8; }
  else              { *Wsel = W[5]; *bsel = bia[5]; *col = 4 + n - 780;    *ld = 8; }
}

// ---------------- prep: layernorm->bf16 (blocks [0,6400)) + weight pack (rest) ----------------
__global__ __launch_bounds__(256) void prep_kernel(const float* __restrict__ e,
                                                   const float* __restrict__ g,
                                                   const float* __restrict__ b,
                                                   unsigned short* __restrict__ elnbf,
                                                   const float* __restrict__ Wq_in,  const float* __restrict__ bq_in,
                                                   const float* __restrict__ Wkv_in, const float* __restrict__ bkv_in,
                                                   const float* __restrict__ Weg_in, const float* __restrict__ beg_in,
                                                   const float* __restrict__ Wq_out, const float* __restrict__ bq_out,
                                                   const float* __restrict__ Wkv_out,const float* __restrict__ bkv_out,
                                                   const float* __restrict__ Weg_out,const float* __restrict__ beg_out,
                                                   const float* __restrict__ Wo,
                                                   unsigned short* __restrict__ WpT, float* __restrict__ bp,
                                                   unsigned short* __restrict__ WoT) {
  if (blockIdx.x < LN_BLOCKS) {
    int row  = blockIdx.x * 4 + (threadIdx.x >> 6);
    int lane = threadIdx.x & 63;
    float4 x = ((const float4*)(e + (long long)row * EDIM))[lane];
    float s = wave_sum(x.x + x.y + x.z + x.w);
    float mu = s * (1.f / EDIM);
    float d0 = x.x - mu, d1 = x.y - mu, d2 = x.z - mu, d3 = x.w - mu;
    float v = wave_sum(d0*d0 + d1*d1 + d2*d2 + d3*d3);
    float rs = rsqrtf(v * (1.f / EDIM) + LNEPS);
    float4 gg = ((const float4*)g)[lane], bb = ((const float4*)b)[lane];
    u16x4 y;
    y[0] = bf16_rne(d0 * rs * gg.x + bb.x);
    y[1] = bf16_rne(d1 * rs * gg.y + bb.y);
    y[2] = bf16_rne(d2 * rs * gg.z + bb.z);
    y[3] = bf16_rne(d3 * rs * gg.w + bb.w);
    *(u16x4*)&elnbf[(long long)row * EDIM + lane * 4] = y;
    return;
  }
  const float* W[6]  = {Wq_in, Wkv_in, Weg_in, Wq_out, Wkv_out, Weg_out};
  const float* bi[6] = {bq_in, bkv_in, beg_in, bq_out, bkv_out, beg_out};
  int idx = (blockIdx.x - LN_BLOCKS) * blockDim.x + threadIdx.x;
  if (idx < PC * 256) {
    int n = idx >> 8, k = idx & 255;
    const float *Ws, *bs; int col, ld; float sc;
    col_map(n, W, bi, &Ws, &bs, &col, &ld, &sc);
    WpT[idx] = bf16_rne(Ws[(long long)k * ld + col] * sc);
  } else if (idx < PC * 256 + PC) {
    int n = idx - PC * 256;
    const float *Ws, *bs; int col, ld; float sc;
    col_map(n, W, bi, &Ws, &bs, &col, &ld, &sc);
    bp[n] = bs[col] * sc;
  } else if (idx < PC * 256 + PC + 256 * 512) {
    int q = idx - (PC * 256 + PC);
    int n = q >> 9, kk = q & 511;
    int brn = kk >> 8, hh = (kk >> 6) & 3, dd = kk & 63;
    WoT[q] = bf16_rne(Wo[(long long)(dd * 8 + hh + 4 * brn) * 256 + n]);
  }
}

// ---------------- projection GEMM (MFMA): Y = eln @ Wp + bp; E/G fused epilogue ----
// 64-col n-tiles, full-K B in LDS, direct A->reg, one staging barrier, coalesced
// Y stores via LDS bounce. Grid 2600 = 13 n-tiles x 200 m-blocks. bg stored half2
// (R9 post-mortem: f32 bg was the 44->56us attn regression; half2 restored).
__global__ __launch_bounds__(512, 8) void proj_kernel(const unsigned short* __restrict__ Abf,
                                                      const unsigned short* __restrict__ WpT,
                                                      const float* __restrict__ bp,
                                                      const float* __restrict__ mask,
                                                      unsigned short* __restrict__ Ybf,
                                                      unsigned short* __restrict__ bgIn,
                                                      unsigned short* __restrict__ bgOut) {
  __shared__ unsigned short Bs[64 * 264];         // 33792 B; reused as Ys[128][66] in epilogue
  const int d = blockIdx.x;
  const int n0t = d / 200;                        // n-tile 0..12
  const int m0 = (d % 200) * 128;
  const int t = threadIdx.x;
  const int lane = t & 63, w = t >> 6;            // w in 0..7
  const int quad = lane >> 4, l15 = lane & 15;
  const int rbase = m0 + w * 16;                  // 16 rows per wave
  const int nbase = n0t * 64;
  const bool tail = (n0t == 12);                  // block-uniform
  const int ncols = tail ? 16 : 64;
  const int ntn   = ncols >> 4;                   // 1 or 4

  const unsigned short* ar0 = Abf + (long long)(rbase + l15) * 256 + quad * 8;

  #pragma unroll
  for (int p = 0; p < 4; ++p) {
    int f = t + p * 512;
    int row = f >> 5, c = (f & 31) << 3;
    if (row < ncols)
      *(u16x8*)&Bs[row * 264 + c] = *(const u16x8*)&WpT[(long long)(nbase + row) * 256 + c];
  }
  __syncthreads();

  f32x4 acc[4];
  #pragma unroll
  for (int c = 0; c < 4; ++c) acc[c] = (f32x4){0.f,0.f,0.f,0.f};

  #pragma unroll 2
  for (int ks = 0; ks < 8; ++ks) {
    bf16x8 a0 = *(const bf16x8*)(ar0 + ks * 32);
    #pragma unroll
    for (int nt = 0; nt < 4; ++nt) {
      if (nt < ntn) {
        bf16x8 bfr = *(const bf16x8*)&Bs[(nt * 16 + l15) * 264 + ks * 32 + quad * 8];
        acc[nt] = __builtin_amdgcn_mfma_f32_16x16x32_bf16(a0, bfr, acc[nt], 0, 0, 0);
      }
    }
  }

  if (!tail) {
    __syncthreads();
    #pragma unroll
    for (int nt = 0; nt < 4; ++nt) {
      float bias = bp[nbase + nt * 16 + l15];
      #pragma unroll
      for (int r = 0; r < 4; ++r)
        Bs[(w * 16 + quad * 4 + r) * 66 + nt * 16 + l15] = bf16_rne(acc[nt][r] + bias);
    }
    __syncthreads();
    #pragma unroll
    for (int it = 0; it < 2; ++it) {
      int f = t + it * 512;
      int row = f >> 3, c = (f & 7) << 3;
      *(u16x8*)&Ybf[(long long)(m0 + row) * YBC + nbase + c] = *(const u16x8*)&Bs[row * 66 + c];
    }
  } else {
    int col = nbase + l15;
    float bias = bp[col];
    #pragma unroll
    for (int r = 0; r < 4; ++r) {
      long long row = rbase + quad * 4 + r;
      float v = acc[0][r] + bias;
      int idx = col - YBC;
      int kind = idx >> 2, h = idx & 3;
      float m = mask[row];
      float x = v + m;
      if (kind & 1) x = 1.f / (1.f + __expf(-x));   // gate
      else          x = x * LOG2E;                  // bias pre-scaled for exp2
      long long rr;
      if (kind < 2) rr = row;
      else {
        int i = (int)(row % NTOK), k = (int)(row / NTOK);
        rr = (long long)i * NTOK + k;
      }
      unsigned short* dst = (kind < 2) ? bgIn : bgOut;
      dst[((long long)h * NNR + rr) * 2 + (kind & 1)] = f2h(x);
    }
  }
}

// ---------------- attention v6: R6 base (half2 bg, strip PV, scatter stores)
// + Vt pad 168->172 (stride 344B: 86dw = 22 mod 32, gcd 2 -> 16-bank start cycle,
//   vs old 84dw = 20 mod 32, gcd 4 -> 8-bank cycle = the 2.8M conflict source)
// + s_setprio(1) around MFMA groups (T5: co-resident blocks at different phases).
// 512 thr / 8 waves = (itile in {0,1}) x (head 0..3). Grid 1600 = 5 i-pairs x 320 (j,br).
// LDS: Kl[160][72] 23,040 + Vt[64][172] 22,016 + Pw[8][16][40] 10,240 = 55,296 B -> 2/CU.
__global__ __launch_bounds__(512, 4) void attn_kernel(const unsigned short* __restrict__ Ybf,
                                                      const unsigned int* __restrict__ bgInU,
                                                      const unsigned int* __restrict__ bgOutU,
                                                      unsigned short* __restrict__ Vab) {
  __shared__ unsigned short smem[27648];          // 55,296 B
  unsigned short (* __restrict__ Kl)[72]      = (unsigned short(*)[72])smem;               // [160][72]
  unsigned short (* __restrict__ Vt)[172]     = (unsigned short(*)[172])(smem + 11520);    // [64][172]
  unsigned short (* __restrict__ Pw)[16][40]  = (unsigned short(*)[16][40])(smem + 22528); // [8][16][40]
  const int d  = blockIdx.x;
  const int jbr = d % 320;
  const int j  = jbr % 160;
  const int br = jbr / 160;
  const int t  = threadIdx.x;
  const int i0 = (d / 320) * 32 + (t >> 8) * 16;  // per-wave i-tile
  const int kb = br ? 640 : 256, vb = kb + 64, qb = br ? 384 : 0;
  const unsigned int* bg = br ? bgOutU : bgInU;

  const int lane = t & 63, h = (t >> 6) & 3;      // wave = (itile, head)
  const int wv = t >> 6;                          // 0..7, P strip index
  const int quad = lane >> 4, l15 = lane & 15;

  // ---- Q B-frags (col i = l15), issued before staging ----
  const unsigned short* qp = &Ybf[((long long)(i0 + l15) * NTOK + j) * YBC + qb + h * 64 + quad * 8];
  bf16x8 q0 = *(const bf16x8*)qp;
  bf16x8 q1 = *(const bf16x8*)(qp + 32);

  // ---- stage K [160][64] ----
  for (int f = t; f < 160 * 8; f += 512) {
    int k = f >> 3, c = (f & 7) << 3;
    long long row = br ? ((long long)k * NTOK + j) : ((long long)j * NTOK + k);
    *(u16x8*)&Kl[k][c] = *(const u16x8*)&Ybf[row * YBC + kb + c];
  }
  // ---- stage V transposed [d][k] (rotated scalar writes) ----
  for (int f = t; f < 160 * 8; f += 512) {
    int k = f >> 3, g = f & 7, c = g << 3;
    long long row = br ? ((long long)k * NTOK + j) : ((long long)j * NTOK + k);
    u16x8 v = *(const u16x8*)&Ybf[row * YBC + vb + c];
    #pragma unroll
    for (int m = 0; m < 8; ++m) { int mm = (m + g) & 7; Vt[c + mm][k] = v[mm]; }
  }
  __syncthreads();                                // the only barrier

  const unsigned int* bgl = bg + (long long)h * NNR + (long long)(i0 + l15) * NTOK;
  unsigned short (* __restrict__ Pr)[40] = Pw[wv];

  float sum = 0.f;
  f32x4 o[4];
  #pragma unroll
  for (int dd = 0; dd < 4; ++dd) o[dd] = (f32x4){0.f,0.f,0.f,0.f};

  #pragma unroll
  for (int ks = 0; ks < 5; ++ks) {
    // ---- swapped QK^T + streaming softmax for k-chunk [32ks, 32ks+32) ----
    #pragma unroll
    for (int nn = 0; nn < 2; ++nn) {
      int n = ks * 2 + nn;
      f32x4 a = (f32x4){0.f,0.f,0.f,0.f};
      __builtin_amdgcn_s_setprio(1);
      a = __builtin_amdgcn_mfma_f32_16x16x32_bf16(*(const bf16x8*)&Kl[n*16 + l15][quad*8],      q0, a, 0, 0, 0);
      a = __builtin_amdgcn_mfma_f32_16x16x32_bf16(*(const bf16x8*)&Kl[n*16 + l15][32 + quad*8], q1, a, 0, 0, 0);
      __builtin_amdgcn_s_setprio(0);
      // a[r] = S^T[kt = n*16+quad*4+r][i = i0+l15]
      uint4 bgv = *(const uint4*)&bgl[n * 16 + quad * 4];
      float p0 = exp2f(a[0] + h2f((unsigned short)(bgv.x & 0xffffu)));
      float p1 = exp2f(a[1] + h2f((unsigned short)(bgv.y & 0xffffu)));
      float p2 = exp2f(a[2] + h2f((unsigned short)(bgv.z & 0xffffu)));
      float p3 = exp2f(a[3] + h2f((unsigned short)(bgv.w & 0xffffu)));
      sum += (p0 + p1) + (p2 + p3);
      uint2 st;
      st.x = pack_bf16(p0 * h2f((unsigned short)(bgv.x >> 16)),
                       p1 * h2f((unsigned short)(bgv.y >> 16)));
      st.y = pack_bf16(p2 * h2f((unsigned short)(bgv.z >> 16)),
                       p3 * h2f((unsigned short)(bgv.w >> 16)));
      *(uint2*)&Pr[l15][nn * 16 + quad * 4] = st; // P[i=l15][klocal]
    }
    // ---- PV: o^T[d][i] += V^T-frag x P^T-frag (wave-private strip readback) ----
    bf16x8 pb = *(const bf16x8*)&Pr[l15][quad * 8];
    __builtin_amdgcn_s_setprio(1);
    #pragma unroll
    for (int dd = 0; dd < 4; ++dd)
      o[dd] = __builtin_amdgcn_mfma_f32_16x16x32_bf16(
                *(const bf16x8*)&Vt[dd * 16 + l15][ks * 32 + quad * 8], pb, o[dd], 0, 0, 0);
    __builtin_amdgcn_s_setprio(0);
  }

  // ---- sum reduce across quads (i = l15 is lane-local) ----
  sum += __shfl_xor(sum, 16, 64);
  sum += __shfl_xor(sum, 32, 64);
  float invs = 1.f / sum;

  // ---- store: lane owns cols [quad*4 .. quad*4+3] of each dd-tile -> dwordx2 ----
  unsigned short* vp = &Vab[((long long)(i0 + l15) * NTOK + j) * 512 + br * 256 + h * 64 + quad * 4];
  #pragma unroll
  for (int dd = 0; dd < 4; ++dd) {
    uint2 st;
    st.x = pack_bf16(o[dd][0] * invs, o[dd][1] * invs);
    st.y = pack_bf16(o[dd][2] * invs, o[dd][3] * invs);
    *(uint2*)(vp + dd * 16) = st;
  }
}

// ---------------- output GEMM (MFMA): out = Va @ WoT^T + bo ----------------
// 1D grid 800: m = d%400 (A-panel sharers spaced 400 -> same XCD), n = d/400
__global__ __launch_bounds__(256) void out_kernel(const unsigned short* __restrict__ Vab,
                                                  const unsigned short* __restrict__ WoT,
                                                  const float* __restrict__ bo,
                                                  float* __restrict__ out) {
  __shared__ unsigned short As[64][72];
  __shared__ unsigned short Bs[128][72];
  const int d = blockIdx.x;
  const int n0 = (d / 400) * 128;
  const int m0 = (d % 400) * 64;
  const int t = threadIdx.x;
  const int lane = t & 63, w = t >> 6;
  const int quad = lane >> 4, l15 = lane & 15;
  f32x4 acc[8];
  #pragma unroll
  for (int c = 0; c < 8; ++c) acc[c] = (f32x4){0.f,0.f,0.f,0.f};
  for (int k0 = 0; k0 < 512; k0 += 64) {
    #pragma unroll
    for (int p = 0; p < 2; ++p) {
      int f = t + p * 256;
      int row = f >> 3, c = (f & 7) << 3;
      *(u16x8*)&As[row][c] = *(const u16x8*)&Vab[(long long)(m0 + row) * 512 + k0 + c];
    }
    #pragma unroll
    for (int p = 0; p < 4; ++p) {
      int f = t + p * 256;
      int row = f >> 3, c = (f & 7) << 3;
      *(u16x8*)&Bs[row][c] = *(const u16x8*)&WoT[(long long)(n0 + row) * 512 + k0 + c];
    }
    __syncthreads();
    #pragma unroll
    for (int ks = 0; ks < 2; ++ks) {
      bf16x8 a0 = *(const bf16x8*)&As[w * 16 + l15][ks * 32 + quad * 8];
      #pragma unroll
      for (int nt = 0; nt < 8; ++nt) {
        bf16x8 bfr = *(const bf16x8*)&Bs[nt * 16 + l15][ks * 32 + quad * 8];
        acc[nt] = __builtin_amdgcn_mfma_f32_16x16x32_bf16(a0, bfr, acc[nt], 0, 0, 0);
      }
    }
    __syncthreads();
  }
  #pragma unroll
  for (int nt = 0; nt < 8; ++nt) {
    int col = n0 + nt * 16 + l15;
    float bias = bo[col];
    #pragma unroll
    for (int r = 0; r < 4; ++r) {
      long long row = m0 + w * 16 + quad * 4 + r;
      out[row * 256 + col] = acc[nt][r] + bias;
    }
  }
}

extern "C" void kernel_launch(void* const* d_in, const int* in_sizes, int n_in,
                              void* d_out, int out_size, void* d_ws, size_t ws_size,
                              hipStream_t stream) {
  const float* e       = (const float*)d_in[0];
  const float* mask    = (const float*)d_in[1];
  const float* ln_g    = (const float*)d_in[2];
  const float* ln_b    = (const float*)d_in[3];
  const float* Wq_in   = (const float*)d_in[4];
  const float* bq_in   = (const float*)d_in[5];
  const float* Wkv_in  = (const float*)d_in[6];
  const float* bkv_in  = (const float*)d_in[7];
  const float* Weg_in  = (const float*)d_in[8];
  const float* beg_in  = (const float*)d_in[9];
  const float* Wq_out  = (const float*)d_in[10];
  const float* bq_out  = (const float*)d_in[11];
  const float* Wkv_out = (const float*)d_in[12];
  const float* bkv_out = (const float*)d_in[13];
  const float* Weg_out = (const float*)d_in[14];
  const float* beg_out = (const float*)d_in[15];
  const float* Wo      = (const float*)d_in[16];
  const float* bo      = (const float*)d_in[17];

  float* ws = (float*)d_ws;
  unsigned short* elnbf = (unsigned short*)(ws + OFF_ELN);
  unsigned short* Ybf   = (unsigned short*)(ws + OFF_YBF);
  unsigned short* WpT   = (unsigned short*)(ws + OFF_WPT);
  float* bp             = ws + OFF_BP;
  unsigned short* WoT   = (unsigned short*)(ws + OFF_WOT);
  unsigned short* bgIn  = (unsigned short*)(ws + OFF_BGI);
  unsigned short* bgOut = (unsigned short*)(ws + OFF_BGO);
  unsigned short* Vab   = (unsigned short*)(ws + OFF_VAB);
  float* outp = (float*)d_out;

  hipLaunchKernelGGL(prep_kernel, dim3(LN_BLOCKS + PACK_BLOCKS), dim3(256), 0, stream,
                     e, ln_g, ln_b, elnbf,
                     Wq_in, bq_in, Wkv_in, bkv_in, Weg_in, beg_in,
                     Wq_out, bq_out, Wkv_out, bkv_out, Weg_out, beg_out, Wo,
                     WpT, bp, WoT);
  hipLaunchKernelGGL(proj_kernel, dim3(2600), dim3(512), 0, stream, elnbf, WpT, bp, mask,
                     Ybf, bgIn, bgOut);
  hipLaunchKernelGGL(attn_kernel, dim3(1600), dim3(512), 0, stream, Ybf,
                     (const unsigned int*)bgIn, (const unsigned int*)bgOut, Vab);
  hipLaunchKernelGGL(out_kernel, dim3(800), dim3(256), 0, stream, Vab, WoT, bo, outp);
}

// Round 11
// 195.711 us; speedup vs baseline: 1.1088x; 1.1088x over previous
//
#include <hip/hip_runtime.h>

#define NTOK 160
#define EDIM 256
#define HH 4
#define NNR 25600          // NTOK*NTOK rows
#define PC 784             // packed projection cols
#define YBC 768            // bf16 matmul cols of Y
#define SCALEF 0.125f
#define LOG2E 1.44269504f
#define LNEPS 1e-5f

// ---- workspace layout (float offsets) ----
#define OFF_ELN 0LL                       // bf16 [NNR][256]
#define OFF_YBF (OFF_ELN + 3276800LL)     // bf16 [NNR][768]
#define OFF_WPT (OFF_YBF + 9830400LL)     // bf16 [784][256]
#define OFF_BP  (OFF_WPT + 100352LL)      // fp32 [784]
#define OFF_WOT (OFF_BP  + 800LL)         // bf16 [256][512]
#define OFF_BGI (OFF_WOT + 65536LL)       // half2 [4][NNR]  (bias*log2e, gate) as uint
#define OFF_BGO (OFF_BGI + 102400LL)      // half2 [4][NNR]
#define OFF_VAB (OFF_BGO + 102400LL)      // bf16 [NNR][512]

#define LN_BLOCKS 6400
#define PACK_TOTAL (PC * 256 + PC + 256 * 512)   // 331,792
#define PACK_BLOCKS ((PACK_TOTAL + 255) / 256)   // 1297

typedef short bf16x8 __attribute__((ext_vector_type(8)));
typedef unsigned short u16x8 __attribute__((ext_vector_type(8)));
typedef unsigned short u16x4 __attribute__((ext_vector_type(4)));
typedef float f32x4 __attribute__((ext_vector_type(4)));

__device__ __forceinline__ unsigned short bf16_rne(float f) {
  unsigned int u = __float_as_uint(f);
  u += 0x7FFFu + ((u >> 16) & 1u);
  return (unsigned short)(u >> 16);
}
__device__ __forceinline__ unsigned int pack_bf16(float lo, float hi) {
  return (unsigned int)bf16_rne(lo) | ((unsigned int)bf16_rne(hi) << 16);
}
__device__ __forceinline__ unsigned short f2h(float f) {
  _Float16 h = (_Float16)f;
  return *(unsigned short*)&h;
}
__device__ __forceinline__ float h2f(unsigned short u) {
  _Float16 h = *(_Float16*)&u;
  return (float)h;
}

__device__ __forceinline__ float wave_sum(float v) {
  #pragma unroll
  for (int o = 1; o < 64; o <<= 1) v += __shfl_xor(v, o, 64);
  return v;
}

// packed col map n: [0,256) Qin(h-major, *SCALE*log2e) | [256,320) Kin | [320,384) Vin |
// [384,640) Qout | [640,704) Kout | [704,768) Vout |
// [768,772) E_in | [772,776) G_in | [776,780) E_out | [780,784) G_out
__device__ __forceinline__ void col_map(int n, const float* const* W, const float* const* bia,
                                        const float** Wsel, const float** bsel,
                                        int* col, int* ld, float* scale) {
  *scale = 1.f;
  if (n < 256)      { *Wsel = W[0]; *bsel = bia[0]; *col = (n&63)*4 + (n>>6); *ld = 256; *scale = SCALEF * LOG2E; }
  else if (n < 320) { *Wsel = W[1]; *bsel = bia[1]; *col = n - 256;        *ld = 128; }
  else if (n < 384) { *Wsel = W[1]; *bsel = bia[1]; *col = 64 + n - 320;   *ld = 128; }
  else if (n < 640) { int c2 = n - 384; *Wsel = W[3]; *bsel = bia[3]; *col = (c2&63)*4 + (c2>>6); *ld = 256; *scale = SCALEF * LOG2E; }
  else if (n < 704) { *Wsel = W[4]; *bsel = bia[4]; *col = n - 640;        *ld = 128; }
  else if (n < 768) { *Wsel = W[4]; *bsel = bia[4]; *col = 64 + n - 704;   *ld = 128; }
  else if (n < 772) { *Wsel = W[2]; *bsel = bia[2]; *col = n - 768;        *ld = 8; }
  else if (n < 776) { *Wsel = W[2]; *bsel = bia[2]; *col = 4 + n - 772;    *ld = 8; }
  else if (n < 780) { *Wsel = W[5]; *bsel = bia[5]; *col = n - 776;        *ld = 8; }
  else              { *Wsel = W[5]; *bsel = bia[5]; *col = 4 + n - 780;    *ld = 8; }
}

// ---------------- prep: layernorm->bf16 (blocks [0,6400)) + weight pack (rest) ----------------
__global__ __launch_bounds__(256) void prep_kernel(const float* __restrict__ e,
                                                   const float* __restrict__ g,
                                                   const float* __restrict__ b,
                                                   unsigned short* __restrict__ elnbf,
                                                   const float* __restrict__ Wq_in,  const float* __restrict__ bq_in,
                                                   const float* __restrict__ Wkv_in, const float* __restrict__ bkv_in,
                                                   const float* __restrict__ Weg_in, const float* __restrict__ beg_in,
                                                   const float* __restrict__ Wq_out, const float* __restrict__ bq_out,
                                                   const float* __restrict__ Wkv_out,const float* __restrict__ bkv_out,
                                                   const float* __restrict__ Weg_out,const float* __restrict__ beg_out,
                                                   const float* __restrict__ Wo,
                                                   unsigned short* __restrict__ WpT, float* __restrict__ bp,
                                                   unsigned short* __restrict__ WoT) {
  if (blockIdx.x < LN_BLOCKS) {
    int row  = blockIdx.x * 4 + (threadIdx.x >> 6);
    int lane = threadIdx.x & 63;
    float4 x = ((const float4*)(e + (long long)row * EDIM))[lane];
    float s = wave_sum(x.x + x.y + x.z + x.w);
    float mu = s * (1.f / EDIM);
    float d0 = x.x - mu, d1 = x.y - mu, d2 = x.z - mu, d3 = x.w - mu;
    float v = wave_sum(d0*d0 + d1*d1 + d2*d2 + d3*d3);
    float rs = rsqrtf(v * (1.f / EDIM) + LNEPS);
    float4 gg = ((const float4*)g)[lane], bb = ((const float4*)b)[lane];
    u16x4 y;
    y[0] = bf16_rne(d0 * rs * gg.x + bb.x);
    y[1] = bf16_rne(d1 * rs * gg.y + bb.y);
    y[2] = bf16_rne(d2 * rs * gg.z + bb.z);
    y[3] = bf16_rne(d3 * rs * gg.w + bb.w);
    *(u16x4*)&elnbf[(long long)row * EDIM + lane * 4] = y;
    return;
  }
  const float* W[6]  = {Wq_in, Wkv_in, Weg_in, Wq_out, Wkv_out, Weg_out};
  const float* bi[6] = {bq_in, bkv_in, beg_in, bq_out, bkv_out, beg_out};
  int idx = (blockIdx.x - LN_BLOCKS) * blockDim.x + threadIdx.x;
  if (idx < PC * 256) {
    int n = idx >> 8, k = idx & 255;
    const float *Ws, *bs; int col, ld; float sc;
    col_map(n, W, bi, &Ws, &bs, &col, &ld, &sc);
    WpT[idx] = bf16_rne(Ws[(long long)k * ld + col] * sc);
  } else if (idx < PC * 256 + PC) {
    int n = idx - PC * 256;
    const float *Ws, *bs; int col, ld; float sc;
    col_map(n, W, bi, &Ws, &bs, &col, &ld, &sc);
    bp[n] = bs[col] * sc;
  } else if (idx < PC * 256 + PC + 256 * 512) {
    int q = idx - (PC * 256 + PC);
    int n = q >> 9, kk = q & 511;
    int brn = kk >> 8, hh = (kk >> 6) & 3, dd = kk & 63;
    WoT[q] = bf16_rne(Wo[(long long)(dd * 8 + hh + 4 * brn) * 256 + n]);
  }
}

// ---------------- projection GEMM (MFMA): Y = eln @ Wp + bp; E/G fused epilogue ----
// 64-col n-tiles, full-K B in LDS, direct A->reg, one staging barrier, coalesced
// Y stores via LDS bounce. Grid 2600 = 13 n-tiles x 200 m-blocks.
// R11: tail-tile bg epilogue de-scattered — transformed values bounce through dead
// Bs LDS, then (bias,gate) pack into ONE uint per (h,row): in-kind = 4x512B
// contiguous stores (was 2B scatters at 8B stride -> ~20MB sector amplification),
// out-kind = one 4B store per word (pair-merged).
__global__ __launch_bounds__(512, 8) void proj_kernel(const unsigned short* __restrict__ Abf,
                                                      const unsigned short* __restrict__ WpT,
                                                      const float* __restrict__ bp,
                                                      const float* __restrict__ mask,
                                                      unsigned short* __restrict__ Ybf,
                                                      unsigned int* __restrict__ bgIn,
                                                      unsigned int* __restrict__ bgOut) {
  __shared__ unsigned short Bs[64 * 264];         // 33792 B; reused as Ys[128][66] / tailF[128][16]
  const int d = blockIdx.x;
  const int n0t = d / 200;                        // n-tile 0..12
  const int m0 = (d % 200) * 128;
  const int t = threadIdx.x;
  const int lane = t & 63, w = t >> 6;            // w in 0..7
  const int quad = lane >> 4, l15 = lane & 15;
  const int rbase = m0 + w * 16;                  // 16 rows per wave
  const int nbase = n0t * 64;
  const bool tail = (n0t == 12);                  // block-uniform
  const int ncols = tail ? 16 : 64;
  const int ntn   = ncols >> 4;                   // 1 or 4

  const unsigned short* ar0 = Abf + (long long)(rbase + l15) * 256 + quad * 8;

  #pragma unroll
  for (int p = 0; p < 4; ++p) {
    int f = t + p * 512;
    int row = f >> 5, c = (f & 31) << 3;
    if (row < ncols)
      *(u16x8*)&Bs[row * 264 + c] = *(const u16x8*)&WpT[(long long)(nbase + row) * 256 + c];
  }
  __syncthreads();

  f32x4 acc[4];
  #pragma unroll
  for (int c = 0; c < 4; ++c) acc[c] = (f32x4){0.f,0.f,0.f,0.f};

  #pragma unroll 2
  for (int ks = 0; ks < 8; ++ks) {
    bf16x8 a0 = *(const bf16x8*)(ar0 + ks * 32);
    #pragma unroll
    for (int nt = 0; nt < 4; ++nt) {
      if (nt < ntn) {
        bf16x8 bfr = *(const bf16x8*)&Bs[(nt * 16 + l15) * 264 + ks * 32 + quad * 8];
        acc[nt] = __builtin_amdgcn_mfma_f32_16x16x32_bf16(a0, bfr, acc[nt], 0, 0, 0);
      }
    }
  }

  if (!tail) {
    __syncthreads();
    #pragma unroll
    for (int nt = 0; nt < 4; ++nt) {
      float bias = bp[nbase + nt * 16 + l15];
      #pragma unroll
      for (int r = 0; r < 4; ++r)
        Bs[(w * 16 + quad * 4 + r) * 66 + nt * 16 + l15] = bf16_rne(acc[nt][r] + bias);
    }
    __syncthreads();
    #pragma unroll
    for (int it = 0; it < 2; ++it) {
      int f = t + it * 512;
      int row = f >> 3, c = (f & 7) << 3;
      *(u16x8*)&Ybf[(long long)(m0 + row) * YBC + nbase + c] = *(const u16x8*)&Bs[row * 66 + c];
    }
  } else {
    // ---- E/G tail: transform -> tailF[128][16] f32 in LDS -> packed uint bg stores ----
    int col = nbase + l15;                        // 768 + l15; kind = l15>>2, h' = l15&3
    float bias = bp[col];
    float* tailF = (float*)Bs;                    // 8 KB of the 33 KB
    __syncthreads();                              // Bs MFMA reads done
    #pragma unroll
    for (int r = 0; r < 4; ++r) {
      int rl = w * 16 + quad * 4 + r;
      float x = acc[0][r] + bias + mask[(long long)(m0 + rl)];
      if (l15 & 4) x = 1.f / (1.f + __expf(-x));  // kinds 1,3: gate sigmoid
      else         x = x * LOG2E;                 // kinds 0,2: bias pre-scaled for exp2
      tailF[rl * 16 + l15] = x;
    }
    __syncthreads();
    int hh = t >> 7, rl = t & 127;                // 4 h-groups x 128 rows
    long long row = m0 + rl;
    unsigned int win = (unsigned int)f2h(tailF[rl * 16 + hh]) |
                       ((unsigned int)f2h(tailF[rl * 16 + 4 + hh]) << 16);
    bgIn[(long long)hh * NNR + row] = win;        // contiguous per h-group
    int i = (int)(row % NTOK), k = (int)(row / NTOK);
    long long rr = (long long)i * NTOK + k;       // transposed for the "out" branch
    unsigned int wout = (unsigned int)f2h(tailF[rl * 16 + 8 + hh]) |
                        ((unsigned int)f2h(tailF[rl * 16 + 12 + hh]) << 16);
    bgOut[(long long)hh * NNR + rr] = wout;       // one 4B store per word
  }
}

// ---------------- attention: EXACT R6 revert (proven 44.0-44.2 us twice) ----
// swapped QK^T + LDS-staged K, strip PV, half2 bg uint4 loads, dwordx2 stores.
// NO Vt pad (168 stride is uniform 2-way on b128 reads), NO setprio (R10: -40%).
// 512 thr / 8 waves = (itile in {0,1}) x (head 0..3). Grid 1600 = 5 i-pairs x 320 (j,br).
// LDS: Kl[160][72] 23,040 + Vt[64][168] 21,504 + Pw[8][16][40] 10,240 = 54,784 B -> 2/CU.
__global__ __launch_bounds__(512, 4) void attn_kernel(const unsigned short* __restrict__ Ybf,
                                                      const unsigned int* __restrict__ bgInU,
                                                      const unsigned int* __restrict__ bgOutU,
                                                      unsigned short* __restrict__ Vab) {
  __shared__ unsigned short Kl[160][72];          // K rows [k][d]
  __shared__ unsigned short Vt[64][168];          // V^T [d][k]
  __shared__ unsigned short Pw[8][16][40];        // per-wave P strip [i][k-local]
  const int d  = blockIdx.x;
  const int jbr = d % 320;
  const int j  = jbr % 160;
  const int br = jbr / 160;
  const int t  = threadIdx.x;
  const int i0 = (d / 320) * 32 + (t >> 8) * 16;  // per-wave i-tile
  const int kb = br ? 640 : 256, vb = kb + 64, qb = br ? 384 : 0;
  const unsigned int* bg = br ? bgOutU : bgInU;

  const int lane = t & 63, h = (t >> 6) & 3;      // wave = (itile, head)
  const int wv = t >> 6;                          // 0..7, P strip index
  const int quad = lane >> 4, l15 = lane & 15;

  // ---- Q B-frags (col i = l15), issued before staging ----
  const unsigned short* qp = &Ybf[((long long)(i0 + l15) * NTOK + j) * YBC + qb + h * 64 + quad * 8];
  bf16x8 q0 = *(const bf16x8*)qp;
  bf16x8 q1 = *(const bf16x8*)(qp + 32);

  // ---- stage K [160][64] ----
  for (int f = t; f < 160 * 8; f += 512) {
    int k = f >> 3, c = (f & 7) << 3;
    long long row = br ? ((long long)k * NTOK + j) : ((long long)j * NTOK + k);
    *(u16x8*)&Kl[k][c] = *(const u16x8*)&Ybf[row * YBC + kb + c];
  }
  // ---- stage V transposed [d][k] (rotated scalar writes) ----
  for (int f = t; f < 160 * 8; f += 512) {
    int k = f >> 3, g = f & 7, c = g << 3;
    long long row = br ? ((long long)k * NTOK + j) : ((long long)j * NTOK + k);
    u16x8 v = *(const u16x8*)&Ybf[row * YBC + vb + c];
    #pragma unroll
    for (int m = 0; m < 8; ++m) { int mm = (m + g) & 7; Vt[c + mm][k] = v[mm]; }
  }
  __syncthreads();                                // the only barrier

  const unsigned int* bgl = bg + (long long)h * NNR + (long long)(i0 + l15) * NTOK;
  unsigned short (* __restrict__ Pr)[40] = Pw[wv];

  float sum = 0.f;
  f32x4 o[4];
  #pragma unroll
  for (int dd = 0; dd < 4; ++dd) o[dd] = (f32x4){0.f,0.f,0.f,0.f};

  #pragma unroll
  for (int ks = 0; ks < 5; ++ks) {
    // ---- swapped QK^T + streaming softmax for k-chunk [32ks, 32ks+32) ----
    #pragma unroll
    for (int nn = 0; nn < 2; ++nn) {
      int n = ks * 2 + nn;                        // A-tile: kt = n*16 + {l15 rows}
      f32x4 a = (f32x4){0.f,0.f,0.f,0.f};
      a = __builtin_amdgcn_mfma_f32_16x16x32_bf16(*(const bf16x8*)&Kl[n*16 + l15][quad*8],      q0, a, 0, 0, 0);
      a = __builtin_amdgcn_mfma_f32_16x16x32_bf16(*(const bf16x8*)&Kl[n*16 + l15][32 + quad*8], q1, a, 0, 0, 0);
      // a[r] = S^T[kt = n*16+quad*4+r][i = i0+l15]
      uint4 bgv = *(const uint4*)&bgl[n * 16 + quad * 4];
      float p0 = exp2f(a[0] + h2f((unsigned short)(bgv.x & 0xffffu)));
      float p1 = exp2f(a[1] + h2f((unsigned short)(bgv.y & 0xffffu)));
      float p2 = exp2f(a[2] + h2f((unsigned short)(bgv.z & 0xffffu)));
      float p3 = exp2f(a[3] + h2f((unsigned short)(bgv.w & 0xffffu)));
      sum += (p0 + p1) + (p2 + p3);
      uint2 st;
      st.x = pack_bf16(p0 * h2f((unsigned short)(bgv.x >> 16)),
                       p1 * h2f((unsigned short)(bgv.y >> 16)));
      st.y = pack_bf16(p2 * h2f((unsigned short)(bgv.z >> 16)),
                       p3 * h2f((unsigned short)(bgv.w >> 16)));
      *(uint2*)&Pr[l15][nn * 16 + quad * 4] = st; // P[i=l15][klocal]
    }
    // ---- PV: o^T[d][i] += V^T-frag x P^T-frag (wave-private strip readback) ----
    bf16x8 pb = *(const bf16x8*)&Pr[l15][quad * 8];
    #pragma unroll
    for (int dd = 0; dd < 4; ++dd)
      o[dd] = __builtin_amdgcn_mfma_f32_16x16x32_bf16(
                *(const bf16x8*)&Vt[dd * 16 + l15][ks * 32 + quad * 8], pb, o[dd], 0, 0, 0);
  }

  // ---- sum reduce across quads (i = l15 is lane-local) ----
  sum += __shfl_xor(sum, 16, 64);
  sum += __shfl_xor(sum, 32, 64);
  float invs = 1.f / sum;

  // ---- store: lane owns cols [quad*4 .. quad*4+3] of each dd-tile -> dwordx2 ----
  unsigned short* vp = &Vab[((long long)(i0 + l15) * NTOK + j) * 512 + br * 256 + h * 64 + quad * 4];
  #pragma unroll
  for (int dd = 0; dd < 4; ++dd) {
    uint2 st;
    st.x = pack_bf16(o[dd][0] * invs, o[dd][1] * invs);
    st.y = pack_bf16(o[dd][2] * invs, o[dd][3] * invs);
    *(uint2*)(vp + dd * 16) = st;
  }
}

// ---------------- output GEMM (MFMA): out = Va @ WoT^T + bo ----------------
// 1D grid 800: m = d%400 (A-panel sharers spaced 400 -> same XCD), n = d/400
__global__ __launch_bounds__(256) void out_kernel(const unsigned short* __restrict__ Vab,
                                                  const unsigned short* __restrict__ WoT,
                                                  const float* __restrict__ bo,
                                                  float* __restrict__ out) {
  __shared__ unsigned short As[64][72];
  __shared__ unsigned short Bs[128][72];
  const int d = blockIdx.x;
  const int n0 = (d / 400) * 128;
  const int m0 = (d % 400) * 64;
  const int t = threadIdx.x;
  const int lane = t & 63, w = t >> 6;
  const int quad = lane >> 4, l15 = lane & 15;
  f32x4 acc[8];
  #pragma unroll
  for (int c = 0; c < 8; ++c) acc[c] = (f32x4){0.f,0.f,0.f,0.f};
  for (int k0 = 0; k0 < 512; k0 += 64) {
    #pragma unroll
    for (int p = 0; p < 2; ++p) {
      int f = t + p * 256;
      int row = f >> 3, c = (f & 7) << 3;
      *(u16x8*)&As[row][c] = *(const u16x8*)&Vab[(long long)(m0 + row) * 512 + k0 + c];
    }
    #pragma unroll
    for (int p = 0; p < 4; ++p) {
      int f = t + p * 256;
      int row = f >> 3, c = (f & 7) << 3;
      *(u16x8*)&Bs[row][c] = *(const u16x8*)&WoT[(long long)(n0 + row) * 512 + k0 + c];
    }
    __syncthreads();
    #pragma unroll
    for (int ks = 0; ks < 2; ++ks) {
      bf16x8 a0 = *(const bf16x8*)&As[w * 16 + l15][ks * 32 + quad * 8];
      #pragma unroll
      for (int nt = 0; nt < 8; ++nt) {
        bf16x8 bfr = *(const bf16x8*)&Bs[nt * 16 + l15][ks * 32 + quad * 8];
        acc[nt] = __builtin_amdgcn_mfma_f32_16x16x32_bf16(a0, bfr, acc[nt], 0, 0, 0);
      }
    }
    __syncthreads();
  }
  #pragma unroll
  for (int nt = 0; nt < 8; ++nt) {
    int col = n0 + nt * 16 + l15;
    float bias = bo[col];
    #pragma unroll
    for (int r = 0; r < 4; ++r) {
      long long row = m0 + w * 16 + quad * 4 + r;
      out[row * 256 + col] = acc[nt][r] + bias;
    }
  }
}

extern "C" void kernel_launch(void* const* d_in, const int* in_sizes, int n_in,
                              void* d_out, int out_size, void* d_ws, size_t ws_size,
                              hipStream_t stream) {
  const float* e       = (const float*)d_in[0];
  const float* mask    = (const float*)d_in[1];
  const float* ln_g    = (const float*)d_in[2];
  const float* ln_b    = (const float*)d_in[3];
  const float* Wq_in   = (const float*)d_in[4];
  const float* bq_in   = (const float*)d_in[5];
  const float* Wkv_in  = (const float*)d_in[6];
  const float* bkv_in  = (const float*)d_in[7];
  const float* Weg_in  = (const float*)d_in[8];
  const float* beg_in  = (const float*)d_in[9];
  const float* Wq_out  = (const float*)d_in[10];
  const float* bq_out  = (const float*)d_in[11];
  const float* Wkv_out = (const float*)d_in[12];
  const float* bkv_out = (const float*)d_in[13];
  const float* Weg_out = (const float*)d_in[14];
  const float* beg_out = (const float*)d_in[15];
  const float* Wo      = (const float*)d_in[16];
  const float* bo      = (const float*)d_in[17];

  float* ws = (float*)d_ws;
  unsigned short* elnbf = (unsigned short*)(ws + OFF_ELN);
  unsigned short* Ybf   = (unsigned short*)(ws + OFF_YBF);
  unsigned short* WpT   = (unsigned short*)(ws + OFF_WPT);
  float* bp             = ws + OFF_BP;
  unsigned short* WoT   = (unsigned short*)(ws + OFF_WOT);
  unsigned int* bgIn    = (unsigned int*)(ws + OFF_BGI);
  unsigned int* bgOut   = (unsigned int*)(ws + OFF_BGO);
  unsigned short* Vab   = (unsigned short*)(ws + OFF_VAB);
  float* outp = (float*)d_out;

  hipLaunchKernelGGL(prep_kernel, dim3(LN_BLOCKS + PACK_BLOCKS), dim3(256), 0, stream,
                     e, ln_g, ln_b, elnbf,
                     Wq_in, bq_in, Wkv_in, bkv_in, Weg_in, beg_in,
                     Wq_out, bq_out, Wkv_out, bkv_out, Weg_out, beg_out, Wo,
                     WpT, bp, WoT);
  hipLaunchKernelGGL(proj_kernel, dim3(2600), dim3(512), 0, stream, elnbf, WpT, bp, mask,
                     Ybf, bgIn, bgOut);
  hipLaunchKernelGGL(attn_kernel, dim3(1600), dim3(512), 0, stream, Ybf,
                     (const unsigned int*)bgIn, (const unsigned int*)bgOut, Vab);
  hipLaunchKernelGGL(out_kernel, dim3(800), dim3(256), 0, stream, Vab, WoT, bo, outp);
}